// Round 4
// baseline (154.644 us; speedup 1.0000x reference)
//
#include <hip/hip_runtime.h>

// ---------------------------------------------------------------------------
// FEM assembly, single-pass gather with sparse row staging.
// Output: stiff (ndof*ndof f32) ++ resid (ndof f32), ndof = 2*nnode.
//
// Each stiffness row has only ~26 nonzeros (deg~6 adjacent elements x 6 cols,
// with overlaps). Instead of staging the full 48 KB row in LDS (round 1:
// 3 blocks/CU, 1.7 GB LDS traffic, ~4.4 TB/s effective), stage only a column
// BITMAP (1.5 KB) + compact (col,val) list (~2 KB). Streaming drain writes
// zeros straight from registers for bitmap-clear groups (99% of the row) and
// linear-scan-sums the list on the rare hits. 8 blocks/CU = 32 waves/CU.
// ---------------------------------------------------------------------------

#define ADJ_CAP  64    // max elements per node; deg ~ Poisson(6), P(>64) ~ 0
#define LIST_CAP 256   // max (col,val) entries per row; 6*deg, P(>256) ~ 0

typedef float fx4 __attribute__((ext_vector_type(4)));  // nontemporal-storable

// ws layout (ints): [cnt: nnode][mask: ndof][adj: nnode*ADJ_CAP]

__global__ void build_adj_kernel(const int* __restrict__ connect, int nelem,
                                 const int* __restrict__ fix_node,
                                 const int* __restrict__ fix_dof, int nfix,
                                 int* __restrict__ cnt,
                                 int* __restrict__ mask,
                                 int* __restrict__ adj) {
    int t = blockIdx.x * blockDim.x + threadIdx.x;
    if (t < nelem) {
#pragma unroll
        for (int v = 0; v < 3; ++v) {
            int n = connect[3 * t + v];
            int slot = atomicAdd(&cnt[n], 1);
            if (slot < ADJ_CAP) adj[n * ADJ_CAP + slot] = (t << 2) | v;
        }
    }
    if (t < nfix) {
        mask[2 * fix_node[t] + fix_dof[t]] = 1;
    }
}

__global__ __launch_bounds__(256) void row_write_kernel(
        const float* __restrict__ x, const float* __restrict__ y,
        const int* __restrict__ connect, const float* __restrict__ mat,
        const int* __restrict__ cnt, const int* __restrict__ mask,
        const int* __restrict__ adj,
        float* __restrict__ stiff, int ndof) {
    __shared__ unsigned int bitmap[512];       // covers ndof <= 16384 cols
    __shared__ int   lcols[LIST_CAP];
    __shared__ float lvals[LIST_CAP];
    __shared__ int   lcount;

    const int r   = blockIdx.x;   // stiffness row
    const int tid = threadIdx.x;
    const int n   = r >> 1;       // node
    const int d   = r & 1;        // dof direction
    const int nwords = (ndof + 31) >> 5;

    for (int i = tid; i < nwords; i += 256) bitmap[i] = 0u;
    if (tid == 0) lcount = 0;
    __syncthreads();

    if (mask[r] != 0) {
        // fixed row: zero row, unit diagonal
        if (tid == 0) {
            lcols[0] = r; lvals[0] = 1.0f; lcount = 1;
            atomicOr(&bitmap[r >> 5], 1u << (r & 31));
        }
    } else {
        int deg = cnt[n];
        if (deg > ADJ_CAP) deg = ADJ_CAP;
        if (tid < deg) {
            const int packed = adj[n * ADJ_CAP + tid];
            const int e  = packed >> 2;
            const int li = packed & 3;   // local index of node n in element e

            const int a = connect[3 * e + 0];
            const int b = connect[3 * e + 1];
            const int c = connect[3 * e + 2];
            const float xa = x[a], xb = x[b], xc = x[c];
            const float ya = y[a], yb = y[b], yc = y[c];

            const float den_a = (ya - yb) * (xc - xb) - (xa - xb) * (yc - yb);
            const float den_b = (yb - yc) * (xa - xc) - (xb - xc) * (ya - yc);
            const float den_c = (yc - ya) * (xb - xa) - (xc - xa) * (yb - ya);

            const float nax = -(yc - yb) / den_a;
            const float nay =  (xc - xb) / den_a;
            const float nbx = -(ya - yc) / den_b;
            const float nby =  (xa - xc) / den_b;
            const float ncx = -(yb - ya) / den_c;
            const float ncy =  (xb - xa) / den_c;

            const float area = 0.5f * fabsf((xb - xa) * (yc - ya) -
                                            (xc - xa) * (yb - ya));

            float nu, E;
            if (mat[e] > 0.5f) { nu = 0.33f; E = 69.0f; }
            else               { nu = 0.30f; E = 200.0f; }
            const float cc  = E / ((1.0f + nu) * (1.0f - 2.0f * nu));
            const float d00 = cc * (1.0f - nu);
            const float d01 = cc * nu;
            const float d22 = cc * (1.0f - 2.0f * nu) * 0.5f;

            const float B0[6] = { nax, 0.f, nbx, 0.f, ncx, 0.f };
            const float B1[6] = { 0.f, nay, 0.f, nby, 0.f, ncy };
            const float B2[6] = { nay, nax, nby, nbx, ncy, ncx };

            // this row's B entries: i = 2*li + d (selects, no runtime array idx)
            const float nx = (li == 0) ? nax : (li == 1) ? nbx : ncx;
            const float ny = (li == 0) ? nay : (li == 1) ? nby : ncy;
            const float Bi0 = (d == 0) ? nx : 0.f;
            const float Bi1 = (d == 0) ? 0.f : ny;
            const float Bi2 = (d == 0) ? ny : nx;

            const int dof[6] = { 2 * a, 2 * a + 1, 2 * b, 2 * b + 1,
                                 2 * c, 2 * c + 1 };
#pragma unroll
            for (int j = 0; j < 6; ++j) {
                const float C0j = d00 * B0[j] + d01 * B1[j];
                const float C1j = d01 * B0[j] + d00 * B1[j];
                const float C2j = d22 * B2[j];
                const float val = area * (Bi0 * C0j + Bi1 * C1j + Bi2 * C2j);
                const int   col = dof[j];
                int slot = atomicAdd(&lcount, 1);
                if (slot < LIST_CAP) {
                    lcols[slot] = col;
                    lvals[slot] = val;    // duplicates summed at drain time
                    atomicOr(&bitmap[col >> 5], 1u << (col & 31));
                }
            }
        }
    }
    __syncthreads();

    // streaming drain: zeros from registers, rare hits from the list
    const int nlist = (lcount < LIST_CAP) ? lcount : LIST_CAP;
    fx4* dst4 = (fx4*)(stiff + (size_t)r * (size_t)ndof);
    const int n4 = ndof >> 2;
    for (int i = tid; i < n4; i += 256) {
        const int c0 = i << 2;
        const unsigned int bits = (bitmap[c0 >> 5] >> (c0 & 31)) & 0xFu;
        fx4 v = (fx4){0.f, 0.f, 0.f, 0.f};
        if (bits) {
            float v0 = 0.f, v1 = 0.f, v2 = 0.f, v3 = 0.f;
            for (int k = 0; k < nlist; ++k) {
                const int   col = lcols[k];
                const float val = lvals[k];
                v0 += (col == c0    ) ? val : 0.f;
                v1 += (col == c0 + 1) ? val : 0.f;
                v2 += (col == c0 + 2) ? val : 0.f;
                v3 += (col == c0 + 3) ? val : 0.f;
            }
            v = (fx4){v0, v1, v2, v3};
        }
        __builtin_nontemporal_store(v, &dst4[i]);
    }
}

__global__ void traction_kernel(const float* __restrict__ x,
                                const float* __restrict__ y,
                                const int* __restrict__ connect,
                                const int* __restrict__ dload_elem,
                                const int* __restrict__ dload_face,
                                const float* __restrict__ tx,
                                const float* __restrict__ ty,
                                float* __restrict__ resid,
                                int ndload) {
    int i = blockIdx.x * blockDim.x + threadIdx.x;
    if (i >= ndload) return;
    int e = dload_elem[i];
    int f = dload_face[i];
    int f2 = (f == 0) ? 1 : (f == 1 ? 2 : 0);   // pointer = [1,2,0]
    int a = connect[3 * e + f];
    int b = connect[3 * e + f2];
    float dx = x[a] - x[b];
    float dy = y[a] - y[b];
    float hl = 0.5f * sqrtf(dx * dx + dy * dy);
    float vx = tx[i] * hl;
    float vy = ty[i] * hl;
    atomicAdd(&resid[2 * a + 0], vx);
    atomicAdd(&resid[2 * a + 1], vy);
    atomicAdd(&resid[2 * b + 0], vx);
    atomicAdd(&resid[2 * b + 1], vy);
}

__global__ void fix_resid_kernel(const int* __restrict__ fix_node,
                                 const int* __restrict__ fix_dof,
                                 const float* __restrict__ fix_val,
                                 float* __restrict__ resid, int nfix) {
    int i = blockIdx.x * blockDim.x + threadIdx.x;
    if (i >= nfix) return;
    int rw = 2 * fix_node[i] + fix_dof[i];
    // last-occurrence-wins (NumPy fancy-assignment semantics)
    bool last = true;
    for (int j = i + 1; j < nfix; ++j) {
        if (2 * fix_node[j] + fix_dof[j] == rw) { last = false; break; }
    }
    if (last) resid[rw] = fix_val[i];
}

extern "C" void kernel_launch(void* const* d_in, const int* in_sizes, int n_in,
                              void* d_out, int out_size, void* d_ws, size_t ws_size,
                              hipStream_t stream) {
    const float* xcoord   = (const float*)d_in[0];
    const float* ycoord   = (const float*)d_in[1];
    const int*   connect  = (const int*)d_in[2];
    const float* emat     = (const float*)d_in[3];
    const int*   dl_elem  = (const int*)d_in[4];
    const int*   dl_face  = (const int*)d_in[5];
    const float* dl_tx    = (const float*)d_in[6];
    const float* dl_ty    = (const float*)d_in[7];
    const int*   fix_node = (const int*)d_in[8];
    const int*   fix_dof  = (const int*)d_in[9];
    const float* fix_val  = (const float*)d_in[10];

    const int nnode  = in_sizes[0];
    const int ndof   = 2 * nnode;
    const int nelem  = in_sizes[3];
    const int ndload = in_sizes[4];
    const int nfix   = in_sizes[8];

    float* stiff = (float*)d_out;
    float* resid = stiff + (size_t)ndof * (size_t)ndof;

    // ws layout (ints): cnt[nnode] | mask[ndof] | adj[nnode*ADJ_CAP]
    int* cnt  = (int*)d_ws;
    int* mask = cnt + nnode;
    int* adj  = mask + ndof;

    // zero cnt+mask (72 KB) and resid (48 KB)
    (void)hipMemsetAsync(d_ws, 0, (size_t)(nnode + ndof) * sizeof(int), stream);
    (void)hipMemsetAsync(resid, 0, (size_t)ndof * sizeof(float), stream);

    // adjacency + fixed-row mask
    {
        int threads = 256;
        int blocks = (nelem + threads - 1) / threads;
        build_adj_kernel<<<blocks, threads, 0, stream>>>(
            connect, nelem, fix_node, fix_dof, nfix, cnt, mask, adj);
    }

    // one block per stiffness row: single full write pass over stiff
    row_write_kernel<<<ndof, 256, 0, stream>>>(
        xcoord, ycoord, connect, emat, cnt, mask, adj, stiff, ndof);

    // residual: traction loads then prescribed values
    {
        int threads = 256;
        int blocks = (ndload + threads - 1) / threads;
        traction_kernel<<<blocks, threads, 0, stream>>>(
            xcoord, ycoord, connect, dl_elem, dl_face, dl_tx, dl_ty,
            resid, ndload);
    }
    {
        int threads = 256;
        int blocks = (nfix + threads - 1) / threads;
        fix_resid_kernel<<<blocks, threads, 0, stream>>>(
            fix_node, fix_dof, fix_val, resid, nfix);
    }
}